// Round 4
// baseline (245.429 us; speedup 1.0000x reference)
//
#include <hip/hip_runtime.h>

typedef __bf16 bf16x8 __attribute__((ext_vector_type(8)));
typedef float  f32x4  __attribute__((ext_vector_type(4)));

#define N_SITES 400000
#define KVOL    27
#define NPAD    (N_SITES + 16)
#define ZROW    N_SITES                  // all-zero row for invalid neighbors

#define FB_BYTES  ((size_t)NPAD * 128)
#define WSB_BYTES ((size_t)KVOL * 8 * 64 * 16)
#define WS_NEED   (FB_BYTES + WSB_BYTES)

// ---------- weight repack: fp32 [27][64][64] -> bf16 MFMA B-fragments ----------
// Fragment (ko, ks, cb), position (lane, e) holds kernel[ko][ci][co],
// ci = ks*32 + (lane>>4)*8 + e, co = cb*16 + (lane&15).
__global__ __launch_bounds__(256) void conv_prep(const float* __restrict__ kern,
                                                 bf16x8* __restrict__ wsb) {
    int tid = blockIdx.x * 256 + threadIdx.x;
    if (tid >= KVOL * 2 * 4 * 64) return;
    int lane = tid & 63;
    int cb   = (tid >> 6) & 3;
    int ks   = (tid >> 8) & 1;
    int ko   = tid >> 9;
    int i = lane & 15, g = lane >> 4;
    int co = cb * 16 + i;
    bf16x8 v;
#pragma unroll
    for (int e = 0; e < 8; ++e) {
        int ci = ks * 32 + g * 8 + e;
        v[e] = (__bf16)kern[(ko * 64 + ci) * 64 + co];
    }
    wsb[tid] = v;
}

// ---------- feats fp32 -> bf16 (plus zero pad rows) ----------
__global__ __launch_bounds__(256) void prep_feats(const float* __restrict__ f,
                                                  bf16x8* __restrict__ dst) {
    int tid = blockIdx.x * 256 + threadIdx.x;
    if (tid >= NPAD * 64 / 8) return;
    bf16x8 v;
    if (tid < N_SITES * 64 / 8) {
        const f32x4* s = (const f32x4*)(f + (size_t)tid * 8);
        f32x4 a = s[0], b = s[1];
#pragma unroll
        for (int e = 0; e < 4; ++e) { v[e] = (__bf16)a[e]; v[e + 4] = (__bf16)b[e]; }
    } else {
#pragma unroll
        for (int e = 0; e < 8; ++e) v[e] = (__bf16)0.0f;
    }
    dst[tid] = v;
}

// ---------- A-fragment set: 32 rows (2 row-tiles) x K=64 (2 halves) ----------
struct AFrag { bf16x8 a0t0, a1t0, a0t1, a1t1; };

__device__ __forceinline__ void gatherA(const bf16x8* __restrict__ fb, int g,
                                        int idx0, int idx1, AFrag& s) {
    const bf16x8* f0 = fb + (((idx0 < 0 ? ZROW : idx0) << 3) + g);
    s.a0t0 = f0[0];
    s.a1t0 = f0[4];
    const bf16x8* f1 = fb + (((idx1 < 0 ? ZROW : idx1) << 3) + g);
    s.a0t1 = f1[0];
    s.a1t1 = f1[4];
}

// ---------- 16 MFMAs: B in registers, A fragment set, 32x64 output ----------
__device__ __forceinline__ void mfma16r(const bf16x8 B[8], const AFrag& s,
                                        f32x4 acc[2][4]) {
#pragma unroll
    for (int cb = 0; cb < 4; ++cb) {
        acc[0][cb] = __builtin_amdgcn_mfma_f32_16x16x32_bf16(s.a0t0, B[cb],     acc[0][cb], 0, 0, 0);
        acc[0][cb] = __builtin_amdgcn_mfma_f32_16x16x32_bf16(s.a1t0, B[4 + cb], acc[0][cb], 0, 0, 0);
        acc[1][cb] = __builtin_amdgcn_mfma_f32_16x16x32_bf16(s.a0t1, B[cb],     acc[1][cb], 0, 0, 0);
        acc[1][cb] = __builtin_amdgcn_mfma_f32_16x16x32_bf16(s.a1t1, B[4 + cb], acc[1][cb], 0, 0, 0);
    }
}

// ---------- main: barrier-free, B double-buffered in registers ----------
// Per iter k (fully unrolled):  load B(k+1) -> regs | MFMA(k) | idx+gather A(k+2).
// No s_barrier in the loop: the compiler's in-order vmcnt tracking leaves
// B(k+1)+A(k+2) in flight across iterations (counted waits, never 0).
__global__ __launch_bounds__(256, 3) void conv_main4(
    const bf16x8* __restrict__ featsb,
    const int*   __restrict__ nmap,
    const float* __restrict__ bias,
    const bf16x8* __restrict__ wsb,
    float* __restrict__ out)
{
    __shared__ __align__(16) int ldsi[KVOL * 128];   // block's nmap slab (13.8 KB)

    const int lane = threadIdx.x & 63;
    const int wave = threadIdx.x >> 6;
    const int i = lane & 15;
    const int g = lane >> 4;
    const int brow = blockIdx.x * 128;
    const int row0 = brow + wave * 32;

    // ---- prologue: stage nmap slab to LDS (27 x 128 ints = 864 x 16B chunks) ----
    {
        const int* nsrc = nmap + brow;
#pragma unroll
        for (int r = 0; r < 3; ++r) {
            int c = r * 256 + threadIdx.x;
            int k = c >> 5, j = c & 31;
            __builtin_amdgcn_global_load_lds(
                (const __attribute__((address_space(1))) char*)
                    ((const char*)(nsrc + (size_t)k * N_SITES + j * 4)),
                (__attribute__((address_space(3))) char*)
                    ((char*)ldsi + (r * 256 + wave * 64) * 16),
                16, 0, 0);
        }
        int c = 768 + threadIdx.x;
        if (c < KVOL * 32) {
            int k = c >> 5, j = c & 31;
            __builtin_amdgcn_global_load_lds(
                (const __attribute__((address_space(1))) char*)
                    ((const char*)(nsrc + (size_t)k * N_SITES + j * 4)),
                (__attribute__((address_space(3))) char*)
                    ((char*)ldsi + (768 + wave * 64) * 16),
                16, 0, 0);
        }
    }

    float bv[4];
#pragma unroll
    for (int cb = 0; cb < 4; ++cb) bv[cb] = bias[cb * 16 + i];

    __syncthreads();   // the only block-wide barrier: idx slab ready

    f32x4 acc[2][4] = {};
    bf16x8 BB[2][8];   // B double-buffer, registers
    AFrag  S[3];       // A distance-2 pipeline

    const bf16x8* bbase = wsb + lane;

    // prologue pipeline fill: B(0), A(0), A(1)
    {
        int j0 = ldsi[0 * 128 + wave * 32 + i];
        int j1 = ldsi[0 * 128 + wave * 32 + 16 + i];
        int j2 = ldsi[1 * 128 + wave * 32 + i];
        int j3 = ldsi[1 * 128 + wave * 32 + 16 + i];
#pragma unroll
        for (int f = 0; f < 8; ++f) BB[0][f] = bbase[f * 64];
        gatherA(featsb, g, j0, j1, S[0]);
        gatherA(featsb, g, j2, j3, S[1]);
    }

#pragma unroll
    for (int k = 0; k < KVOL; ++k) {
        __builtin_amdgcn_sched_barrier(0);
        if (k + 1 < KVOL) {                      // B(k+1) -> other reg set (8 vmem)
#pragma unroll
            for (int f = 0; f < 8; ++f)
                BB[(k + 1) & 1][f] = bbase[((k + 1) * 8 + f) * 64];
        }
        __builtin_amdgcn_sched_barrier(0);
        __builtin_amdgcn_s_setprio(1);
        mfma16r(BB[k & 1], S[k % 3], acc);       // compiler emits counted vmcnt here
        __builtin_amdgcn_s_setprio(0);
        __builtin_amdgcn_sched_barrier(0);
        if (k + 2 < KVOL) {                      // idx + gather A(k+2) (4 vmem)
            int j0 = ldsi[(k + 2) * 128 + wave * 32 + i];
            int j1 = ldsi[(k + 2) * 128 + wave * 32 + 16 + i];
            gatherA(featsb, g, j0, j1, S[(k + 2) % 3]);
        }
        __builtin_amdgcn_sched_barrier(0);
    }

    // ---- epilogue stores: C/D layout col = lane&15, row = (lane>>4)*4 + reg ----
#pragma unroll
    for (int t = 0; t < 2; ++t)
#pragma unroll
        for (int cb = 0; cb < 4; ++cb)
#pragma unroll
            for (int r = 0; r < 4; ++r)
                __builtin_nontemporal_store(acc[t][cb][r] + bv[cb],
                    &out[(size_t)(row0 + t * 16 + g * 4 + r) * 64 + cb * 16 + i]);
}

// ---------- fallback (only if ws too small): round-1 kernel ----------
__global__ __launch_bounds__(256) void conv_main1(
    const float* __restrict__ feats,
    const int*   __restrict__ nmap,
    const float* __restrict__ bias,
    const bf16x8* __restrict__ wsb,
    float* __restrict__ out)
{
    const int lane = threadIdx.x & 63;
    const int wave = threadIdx.x >> 6;
    const int i = lane & 15;
    const int g = lane >> 4;
    const int row0 = (blockIdx.x * 4 + wave) * 32;

    f32x4 acc[2][4] = {};
    for (int k = 0; k < KVOL; ++k) {
        bf16x8 bfr[2][4];
#pragma unroll
        for (int ks = 0; ks < 2; ++ks)
#pragma unroll
            for (int cb = 0; cb < 4; ++cb)
                bfr[ks][cb] = wsb[(k * 8 + ks * 4 + cb) * 64 + lane];
#pragma unroll
        for (int t = 0; t < 2; ++t) {
            const int row = row0 + t * 16 + i;
            const int idx = nmap[k * N_SITES + row];
            const int src = idx < 0 ? 0 : idx;
            const f32x4* fp = (const f32x4*)(feats + (size_t)src * 64 + g * 8);
            f32x4 v0 = fp[0], v1 = fp[1], v2 = fp[8], v3 = fp[9];
            union { bf16x8 v; unsigned u[4]; } A0, A1;
#pragma unroll
            for (int e = 0; e < 4; ++e) {
                A0.v[e] = (__bf16)v0[e]; A0.v[e + 4] = (__bf16)v1[e];
                A1.v[e] = (__bf16)v2[e]; A1.v[e + 4] = (__bf16)v3[e];
            }
#pragma unroll
            for (int e = 0; e < 4; ++e) {
                A0.u[e] = (idx < 0) ? 0u : A0.u[e];
                A1.u[e] = (idx < 0) ? 0u : A1.u[e];
            }
#pragma unroll
            for (int cb = 0; cb < 4; ++cb)
                acc[t][cb] = __builtin_amdgcn_mfma_f32_16x16x32_bf16(A0.v, bfr[0][cb], acc[t][cb], 0, 0, 0);
#pragma unroll
            for (int cb = 0; cb < 4; ++cb)
                acc[t][cb] = __builtin_amdgcn_mfma_f32_16x16x32_bf16(A1.v, bfr[1][cb], acc[t][cb], 0, 0, 0);
        }
    }
    float bv[4];
#pragma unroll
    for (int cb = 0; cb < 4; ++cb) bv[cb] = bias[cb * 16 + i];
#pragma unroll
    for (int t = 0; t < 2; ++t)
#pragma unroll
        for (int cb = 0; cb < 4; ++cb)
#pragma unroll
            for (int r = 0; r < 4; ++r)
                out[(size_t)(row0 + t * 16 + g * 4 + r) * 64 + cb * 16 + i] =
                    acc[t][cb][r] + bv[cb];
}

extern "C" void kernel_launch(void* const* d_in, const int* in_sizes, int n_in,
                              void* d_out, int out_size, void* d_ws, size_t ws_size,
                              hipStream_t stream) {
    const float* feats = (const float*)d_in[0];
    const float* kern  = (const float*)d_in[1];
    const float* bias  = (const float*)d_in[2];
    const int*   nmap  = (const int*)d_in[3];
    float* out = (float*)d_out;

    if (ws_size >= WS_NEED) {
        bf16x8* fb  = (bf16x8*)d_ws;
        bf16x8* wsb = (bf16x8*)((char*)d_ws + FB_BYTES);
        prep_feats<<<(NPAD * 64 / 8 + 255) / 256, 256, 0, stream>>>(feats, fb);
        conv_prep<<<(KVOL * 2 * 4 * 64 + 255) / 256, 256, 0, stream>>>(kern, wsb);
        // 32 rows/wave, 4 waves/block -> 128 rows/block; 400000/128 = 3125 exactly
        conv_main4<<<3125, 256, 0, stream>>>(fb, nmap, bias, wsb, out);
    } else {
        bf16x8* wsb = (bf16x8*)d_ws;
        conv_prep<<<(KVOL * 2 * 4 * 64 + 255) / 256, 256, 0, stream>>>(kern, wsb);
        conv_main1<<<3125, 256, 0, stream>>>(feats, nmap, bias, wsb, out);
    }
}

// Round 5
// 195.972 us; speedup vs baseline: 1.2524x; 1.2524x over previous
//
#include <hip/hip_runtime.h>

typedef __bf16 bf16x8 __attribute__((ext_vector_type(8)));
typedef float  f32x4  __attribute__((ext_vector_type(4)));

#define N_SITES 400000
#define KVOL    27
#define NPAD    (N_SITES + 16)
#define ZROW    N_SITES                  // all-zero row for invalid neighbors

#define FB_BYTES  ((size_t)NPAD * 128)
#define WSB_BYTES ((size_t)KVOL * 8 * 64 * 16)
#define WS_NEED   (FB_BYTES + WSB_BYTES)

// ---------- weight repack: fp32 [27][64][64] -> bf16 MFMA B-fragments ----------
// Fragment (ko, ks, cb), position (lane, e) holds kernel[ko][ci][co],
// ci = ks*32 + (lane>>4)*8 + e, co = cb*16 + (lane&15).
__global__ __launch_bounds__(256) void conv_prep(const float* __restrict__ kern,
                                                 bf16x8* __restrict__ wsb) {
    int tid = blockIdx.x * 256 + threadIdx.x;
    if (tid >= KVOL * 2 * 4 * 64) return;
    int lane = tid & 63;
    int cb   = (tid >> 6) & 3;
    int ks   = (tid >> 8) & 1;
    int ko   = tid >> 9;
    int i = lane & 15, g = lane >> 4;
    int co = cb * 16 + i;
    bf16x8 v;
#pragma unroll
    for (int e = 0; e < 8; ++e) {
        int ci = ks * 32 + g * 8 + e;
        v[e] = (__bf16)kern[(ko * 64 + ci) * 64 + co];
    }
    wsb[tid] = v;
}

// ---------- feats fp32 -> bf16 (plus zero pad rows) ----------
__global__ __launch_bounds__(256) void prep_feats(const float* __restrict__ f,
                                                  bf16x8* __restrict__ dst) {
    int tid = blockIdx.x * 256 + threadIdx.x;
    if (tid >= NPAD * 64 / 8) return;
    bf16x8 v;
    if (tid < N_SITES * 64 / 8) {
        const f32x4* s = (const f32x4*)(f + (size_t)tid * 8);
        f32x4 a = s[0], b = s[1];
#pragma unroll
        for (int e = 0; e < 4; ++e) { v[e] = (__bf16)a[e]; v[e + 4] = (__bf16)b[e]; }
    } else {
#pragma unroll
        for (int e = 0; e < 8; ++e) v[e] = (__bf16)0.0f;
    }
    dst[tid] = v;
}

// ---------- async global->LDS stage of one offset's B fragments (8 KB) ----------
__device__ __forceinline__ void stage_b(const bf16x8* __restrict__ wsb, int k,
                                        char* buf) {
    const char* g = (const char*)(wsb + (size_t)k * 8 * 64);
    int wave = threadIdx.x >> 6;
    int t    = threadIdx.x;
    __builtin_amdgcn_global_load_lds(
        (const __attribute__((address_space(1))) char*)(g + (size_t)t * 16),
        (__attribute__((address_space(3))) char*)(buf + wave * 1024), 16, 0, 0);
    __builtin_amdgcn_global_load_lds(
        (const __attribute__((address_space(1))) char*)(g + 4096 + (size_t)t * 16),
        (__attribute__((address_space(3))) char*)(buf + 4096 + wave * 1024), 16, 0, 0);
}

// ---------- A-fragment set: 32 rows (2 row-tiles) x K=64 (2 halves) ----------
struct AFrag { bf16x8 a0t0, a1t0, a0t1, a1t1; };

__device__ __forceinline__ void gatherA(const bf16x8* __restrict__ fb, int g,
                                        int idx0, int idx1, AFrag& s) {
    const bf16x8* f0 = fb + (((idx0 < 0 ? ZROW : idx0) << 3) + g);
    s.a0t0 = f0[0];
    s.a1t0 = f0[4];
    const bf16x8* f1 = fb + (((idx1 < 0 ? ZROW : idx1) << 3) + g);
    s.a0t1 = f1[0];
    s.a1t1 = f1[4];
}

__device__ __forceinline__ void mfma16(const char* bbuf, int lane,
                                       const AFrag& s, f32x4 acc[2][4]) {
    const bf16x8* B = (const bf16x8*)bbuf;
#pragma unroll
    for (int cb = 0; cb < 4; ++cb) {
        bf16x8 b0 = B[cb * 64 + lane];
        bf16x8 b1 = B[(4 + cb) * 64 + lane];
        acc[0][cb] = __builtin_amdgcn_mfma_f32_16x16x32_bf16(s.a0t0, b0, acc[0][cb], 0, 0, 0);
        acc[0][cb] = __builtin_amdgcn_mfma_f32_16x16x32_bf16(s.a1t0, b1, acc[0][cb], 0, 0, 0);
        acc[1][cb] = __builtin_amdgcn_mfma_f32_16x16x32_bf16(s.a0t1, b0, acc[1][cb], 0, 0, 0);
        acc[1][cb] = __builtin_amdgcn_mfma_f32_16x16x32_bf16(s.a1t1, b1, acc[1][cb], 0, 0, 0);
    }
}

// ---------- steady-state body, k in [0,24) ----------
// vmem issue order per iter:  stage B(k+2) [2]  then  gather A(k+2) [4].
// Barrier waits vmcnt(10): stage(k+1) (issued LAST iteration, fully latency-
// covered) must be done; everything newer (4+2+4=10) stays in flight.
__device__ __forceinline__ void body(int k,
    const bf16x8* __restrict__ fb, const bf16x8* __restrict__ wsb,
    char (*ldsb)[8192], const int* ldsi, int lane, int wave, int g,
    AFrag& cur, AFrag& nxt2, int iu0, int iu1, int& il0, int& il1,
    f32x4 acc[2][4])
{
    __builtin_amdgcn_sched_barrier(0);
    stage_b(wsb, k + 2, ldsb[(k + 2) % 3]);      // 2 vmem, distance-2
    __builtin_amdgcn_sched_barrier(0);
    gatherA(fb, g, iu0, iu1, nxt2);              // 4 vmem, for k+2
    il0 = ldsi[(k + 3) * 128 + wave * 32 + (lane & 15)];        // idx(k+3)
    il1 = ldsi[(k + 3) * 128 + wave * 32 + 16 + (lane & 15)];
    __builtin_amdgcn_sched_barrier(0);
    mfma16(ldsb[k % 3], lane, cur, acc);
    __builtin_amdgcn_sched_barrier(0);
    asm volatile("s_waitcnt vmcnt(10)" ::: "memory");
    __builtin_amdgcn_sched_barrier(0);
    __builtin_amdgcn_s_barrier();
}

__global__ __launch_bounds__(256, 4) void conv_main5(
    const bf16x8* __restrict__ featsb,
    const int*   __restrict__ nmap,
    const float* __restrict__ bias,
    const bf16x8* __restrict__ wsb,
    float* __restrict__ out)
{
    __shared__ __align__(1024) char ldsb[3][8192];      // triple-buffered B
    __shared__ __align__(16)   int  ldsi[KVOL * 128];   // block's nmap slab

    const int lane = threadIdx.x & 63;
    const int wave = threadIdx.x >> 6;
    const int i = lane & 15;
    const int g = lane >> 4;
    const int brow = blockIdx.x * 128;
    const int row0 = brow + wave * 32;

    // ---- prologue: stage nmap slab (27 x 128 ints = 864 x 16B chunks) ----
    {
        const int* nsrc = nmap + brow;
#pragma unroll
        for (int r = 0; r < 3; ++r) {
            int c = r * 256 + threadIdx.x;
            int k = c >> 5, j = c & 31;
            __builtin_amdgcn_global_load_lds(
                (const __attribute__((address_space(1))) char*)
                    ((const char*)(nsrc + (size_t)k * N_SITES + j * 4)),
                (__attribute__((address_space(3))) char*)
                    ((char*)ldsi + (r * 256 + wave * 64) * 16),
                16, 0, 0);
        }
        int c = 768 + threadIdx.x;
        if (c < KVOL * 32) {
            int k = c >> 5, j = c & 31;
            __builtin_amdgcn_global_load_lds(
                (const __attribute__((address_space(1))) char*)
                    ((const char*)(nsrc + (size_t)k * N_SITES + j * 4)),
                (__attribute__((address_space(3))) char*)
                    ((char*)ldsi + (768 + wave * 64) * 16),
                16, 0, 0);
        }
    }
    stage_b(wsb, 0, ldsb[0]);
    stage_b(wsb, 1, ldsb[1]);

    float bv[4];
#pragma unroll
    for (int cb = 0; cb < 4; ++cb) bv[cb] = bias[cb * 16 + i];

    __syncthreads();   // full drain once: slab + B(0) + B(1) ready

    f32x4 acc[2][4] = {};
    AFrag S0, S1, S2;
    int I0t0, I0t1, I1t0, I1t1, I2t0, I2t1;

    I0t0 = ldsi[0 * 128 + wave * 32 + i];  I0t1 = ldsi[0 * 128 + wave * 32 + 16 + i];
    I1t0 = ldsi[1 * 128 + wave * 32 + i];  I1t1 = ldsi[1 * 128 + wave * 32 + 16 + i];
    I2t0 = ldsi[2 * 128 + wave * 32 + i];  I2t1 = ldsi[2 * 128 + wave * 32 + 16 + i];
    gatherA(featsb, g, I0t0, I0t1, S0);    // A_0
    gatherA(featsb, g, I1t0, I1t1, S1);    // A_1

    // iter k: uses S[k%3], B-buf k%3; writes S[(k+2)%3]; consumes I[(k+2)%3];
    // loads idx(k+3) into I[k%3].  24 = 8 x 3 steady iterations.
#pragma unroll 1
    for (int j = 0; j < 8; ++j) {
        int k = j * 3;
        body(k,     featsb, wsb, ldsb, ldsi, lane, wave, g, S0, S2, I2t0, I2t1, I0t0, I0t1, acc);
        body(k + 1, featsb, wsb, ldsb, ldsi, lane, wave, g, S1, S0, I0t0, I0t1, I1t0, I1t1, acc);
        body(k + 2, featsb, wsb, ldsb, ldsi, lane, wave, g, S2, S1, I1t0, I1t1, I2t0, I2t1, acc);
    }

    // ---- tail: k = 24, 25, 26 ----
    // k=24: stage B(26)->buf2, gather A(26) (idx in I2), MFMA buf0/S0
    __builtin_amdgcn_sched_barrier(0);
    stage_b(wsb, 26, ldsb[2]);
    __builtin_amdgcn_sched_barrier(0);
    gatherA(featsb, g, I2t0, I2t1, S2);
    __builtin_amdgcn_sched_barrier(0);
    mfma16(ldsb[0], lane, S0, acc);
    __builtin_amdgcn_sched_barrier(0);
    asm volatile("s_waitcnt vmcnt(10)" ::: "memory");   // drains stage(25)
    __builtin_amdgcn_sched_barrier(0);
    __builtin_amdgcn_s_barrier();
    // k=25: MFMA buf1/S1
    __builtin_amdgcn_sched_barrier(0);
    mfma16(ldsb[1], lane, S1, acc);
    __builtin_amdgcn_sched_barrier(0);
    asm volatile("s_waitcnt vmcnt(4)" ::: "memory");    // drains stage(26)
    __builtin_amdgcn_sched_barrier(0);
    __builtin_amdgcn_s_barrier();
    // k=26: MFMA buf2/S2 (compiler waits gather(26))
    mfma16(ldsb[2], lane, S2, acc);

    // ---- epilogue stores: C/D layout col = lane&15, row = (lane>>4)*4 + reg ----
#pragma unroll
    for (int t = 0; t < 2; ++t)
#pragma unroll
        for (int cb = 0; cb < 4; ++cb)
#pragma unroll
            for (int r = 0; r < 4; ++r)
                __builtin_nontemporal_store(acc[t][cb][r] + bv[cb],
                    &out[(size_t)(row0 + t * 16 + g * 4 + r) * 64 + cb * 16 + i]);
}

// ---------- fallback (only if ws too small): round-1 kernel ----------
__global__ __launch_bounds__(256) void conv_main1(
    const float* __restrict__ feats,
    const int*   __restrict__ nmap,
    const float* __restrict__ bias,
    const bf16x8* __restrict__ wsb,
    float* __restrict__ out)
{
    const int lane = threadIdx.x & 63;
    const int wave = threadIdx.x >> 6;
    const int i = lane & 15;
    const int g = lane >> 4;
    const int row0 = (blockIdx.x * 4 + wave) * 32;

    f32x4 acc[2][4] = {};
    for (int k = 0; k < KVOL; ++k) {
        bf16x8 bfr[2][4];
#pragma unroll
        for (int ks = 0; ks < 2; ++ks)
#pragma unroll
            for (int cb = 0; cb < 4; ++cb)
                bfr[ks][cb] = wsb[(k * 8 + ks * 4 + cb) * 64 + lane];
#pragma unroll
        for (int t = 0; t < 2; ++t) {
            const int row = row0 + t * 16 + i;
            const int idx = nmap[k * N_SITES + row];
            const int src = idx < 0 ? 0 : idx;
            const f32x4* fp = (const f32x4*)(feats + (size_t)src * 64 + g * 8);
            f32x4 v0 = fp[0], v1 = fp[1], v2 = fp[8], v3 = fp[9];
            union { bf16x8 v; unsigned u[4]; } A0, A1;
#pragma unroll
            for (int e = 0; e < 4; ++e) {
                A0.v[e] = (__bf16)v0[e]; A0.v[e + 4] = (__bf16)v1[e];
                A1.v[e] = (__bf16)v2[e]; A1.v[e + 4] = (__bf16)v3[e];
            }
#pragma unroll
            for (int e = 0; e < 4; ++e) {
                A0.u[e] = (idx < 0) ? 0u : A0.u[e];
                A1.u[e] = (idx < 0) ? 0u : A1.u[e];
            }
#pragma unroll
            for (int cb = 0; cb < 4; ++cb)
                acc[t][cb] = __builtin_amdgcn_mfma_f32_16x16x32_bf16(A0.v, bfr[0][cb], acc[t][cb], 0, 0, 0);
#pragma unroll
            for (int cb = 0; cb < 4; ++cb)
                acc[t][cb] = __builtin_amdgcn_mfma_f32_16x16x32_bf16(A1.v, bfr[1][cb], acc[t][cb], 0, 0, 0);
        }
    }
    float bv[4];
#pragma unroll
    for (int cb = 0; cb < 4; ++cb) bv[cb] = bias[cb * 16 + i];
#pragma unroll
    for (int t = 0; t < 2; ++t)
#pragma unroll
        for (int cb = 0; cb < 4; ++cb)
#pragma unroll
            for (int r = 0; r < 4; ++r)
                out[(size_t)(row0 + t * 16 + g * 4 + r) * 64 + cb * 16 + i] =
                    acc[t][cb][r] + bv[cb];
}

extern "C" void kernel_launch(void* const* d_in, const int* in_sizes, int n_in,
                              void* d_out, int out_size, void* d_ws, size_t ws_size,
                              hipStream_t stream) {
    const float* feats = (const float*)d_in[0];
    const float* kern  = (const float*)d_in[1];
    const float* bias  = (const float*)d_in[2];
    const int*   nmap  = (const int*)d_in[3];
    float* out = (float*)d_out;

    if (ws_size >= WS_NEED) {
        bf16x8* fb  = (bf16x8*)d_ws;
        bf16x8* wsb = (bf16x8*)((char*)d_ws + FB_BYTES);
        prep_feats<<<(NPAD * 64 / 8 + 255) / 256, 256, 0, stream>>>(feats, fb);
        conv_prep<<<(KVOL * 2 * 4 * 64 + 255) / 256, 256, 0, stream>>>(kern, wsb);
        // 32 rows/wave, 4 waves/block -> 128 rows/block; 400000/128 = 3125 exactly
        conv_main5<<<3125, 256, 0, stream>>>(fb, nmap, bias, wsb, out);
    } else {
        bf16x8* wsb = (bf16x8*)d_ws;
        conv_prep<<<(KVOL * 2 * 4 * 64 + 255) / 256, 256, 0, stream>>>(kern, wsb);
        conv_main1<<<3125, 256, 0, stream>>>(feats, nmap, bias, wsb, out);
    }
}